// Round 14
// baseline (258.917 us; speedup 1.0000x reference)
//
#include <hip/hip_runtime.h>
#include <stdint.h>

// SimpleAttention v14: v13 + counted-wait barriers. __syncthreads drains
// vmcnt(0) [HIP-compiler]; all cross-wave deps here are via LDS, so
// "s_waitcnt lgkmcnt(0); s_barrier" suffices and leaves global loads/stores
// in flight across barriers (T4). issue(0) hoisted under phase-A softmax.

typedef unsigned int uint_t;
typedef float  f32x4   __attribute__((ext_vector_type(4)));
typedef short  short8v __attribute__((ext_vector_type(8)));

#define SYNCX() asm volatile("s_waitcnt lgkmcnt(0)\n\ts_barrier" ::: "memory")

constexpr int Bq = 16, Cq = 3072, Tq = 2048;
constexpr int TT = 32, TILES = 64, NBLK = Bq * TILES;   // 1024 blocks
constexpr size_t ATT_OFF = (size_t)Bq * 2048 * Tq;
constexpr int TBS = 4224;                 // per-t staging block stride (bytes)
constexpr int LDS_BYTES = 135168;         // 32*TBS == 1024*33*4 (unioned with olds)

__global__ __launch_bounds__(1024, 1) void attn_v14(const float* __restrict__ x,
                                                    const float* __restrict__ xi,
                                                    float* __restrict__ out)
{
    __shared__ __align__(16) unsigned char smem[LDS_BYTES];
    uint_t*    LW = (uint_t*)smem;
    uint64_t*  LQ = (uint64_t*)smem;
    float*     LF = (float*)smem;

    const int tid  = (int)threadIdx.x;
    const int b    = (int)blockIdx.x >> 6;
    const int tile = (int)blockIdx.x & (TILES - 1);
    const int t0   = tile * TT;
    const int tl   = tid & 31;           // t for phase A / staging / stores
    const int slot = tid >> 5;           // 0..31: i (phase A, P-stage), d (C-stage, store)

    const float* xb  = x  + (size_t)b * Cq * Tq + t0 + tl;
    const float* xib = xi + (size_t)b * Cq * Tq + t0 + tl;

    uint_t pk[32];
    float  cre[32];                      // ctx prefetch buffer (one chunk ahead)

    auto issue = [&](int c) {            // c = dh*2 + jh, literal-called only
        const int dh = c >> 1, jh = c & 1;
        const float* src = (jh == 0) ? x : xi;
        const float* sp  = src + (size_t)b * Cq * Tq
                         + (size_t)(32 + dh * 32 + slot) * Tq + t0 + tl;
#pragma unroll
        for (int kk = 0; kk < 32; ++kk) cre[kk] = sp[(size_t)kk * 96 * Tq];
    };

    // ---- phase A: softmax row i=slot; attn out; pack p -> pk ----
    {
        const int i = slot;
        float p[64];
#pragma unroll
        for (int j = 0; j < 32; ++j) p[j]      = xb [(size_t)(i * 96 + j) * Tq];
#pragma unroll
        for (int j = 0; j < 32; ++j) p[j + 32] = xib[(size_t)(i * 96 + j) * Tq];

        issue(0);                        // chunk-0 ctx loads fly under softmax

        float m = p[0];
#pragma unroll
        for (int j = 1; j < 64; ++j) m = fmaxf(m, p[j]);
        float s = 0.f;
#pragma unroll
        for (int j = 0; j < 64; ++j) { p[j] = __expf(p[j] - m); s += p[j]; }
        const float inv = 1.f / s;
#pragma unroll
        for (int j = 0; j < 64; ++j) p[j] *= inv;

        float* ao = out + ATT_OFF + ((size_t)(b * 32 + i) * 32) * Tq + t0 + tl;
#pragma unroll
        for (int j = 0; j < 32; ++j) {
            float v = p[j] + ((j == i) ? 0.f : p[j + 32]);
            __builtin_nontemporal_store(v, &ao[(size_t)j * Tq]);
        }
#pragma unroll
        for (int k = 0; k < 32; ++k) {
            uint_t b0 = __float_as_uint(p[2 * k]);
            uint_t b1 = __float_as_uint(p[2 * k + 1]);
            uint_t lo = (b0 + 0x7fffu + ((b0 >> 16) & 1u)) >> 16;
            uint_t hi = (b1 + 0x7fffu + ((b1 >> 16) & 1u)) >> 16;
            pk[k] = lo | (hi << 16);
        }
    }

    // staging-side constants (row = slot)
    const int fw  = ((slot >> 2) & 3) ^ (slot & 3);      // kb-XOR swizzle
    const int TBw = tl * TBS + (tl & 7) * 16;            // t-block byte base

    // mfma-side constants
    const int l   = tid & 63;
    const int wv  = tid >> 6;                            // wave owns t = 2wv, 2wv+1
    const int frd = ((l >> 2) & 3) ^ (l & 3);
    const int kbr = (((l >> 4) ^ frd) & 3) * 16;
    const int rA  = (l & 15) * 64;

    auto stageP = [&](int jh) {
#pragma unroll
        for (int m = 0; m < 16; m += 2) {                // pairs (m, m+1) share kb
            const int kbx  = (m >> 2) ^ fw;
            const int byte = TBw + slot * 64 + kbx * 16 + ((2 * m) & 7) * 2;
            uint64_t w = (uint64_t)pk[jh * 16 + m] |
                         ((uint64_t)pk[jh * 16 + m + 1] << 32);
            LQ[byte >> 3] = w;
        }
    };
    auto stageC = [&]() {                                 // consumes cre[]
#pragma unroll
        for (int kk = 0; kk < 32; kk += 2) {
            uint_t b0 = __float_as_uint(cre[kk]);
            uint_t b1 = __float_as_uint(cre[kk + 1]);
            uint_t h0 = (b0 + 0x7fffu + ((b0 >> 16) & 1u)) >> 16;
            uint_t h1 = (b1 + 0x7fffu + ((b1 >> 16) & 1u)) >> 16;
            const int kbx  = (kk >> 3) ^ fw;
            const int byte = TBw + 2048 + slot * 64 + kbx * 16 + (kk & 7) * 2;
            LW[byte >> 2] = h0 | (h1 << 16);
        }
    };

    f32x4 acc[2][2][2];                                  // [q][s][dt]
    auto accClr = [&]() {
#pragma unroll
        for (int q = 0; q < 2; ++q)
#pragma unroll
            for (int s = 0; s < 2; ++s)
#pragma unroll
                for (int dt = 0; dt < 2; ++dt) acc[q][s][dt] = (f32x4)(0.f);
    };
    auto mfmaChunk = [&]() {
#pragma unroll
        for (int q = 0; q < 2; ++q) {
            const int tloc = 2 * wv + q;
            const int base = tloc * TBS + (tloc & 7) * 16;
            const short8v A0 = *(const short8v*)(smem + base        + rA + kbr);
            const short8v A1 = *(const short8v*)(smem + base + 1024 + rA + kbr);
            const short8v B0 = *(const short8v*)(smem + base + 2048 + rA + kbr);
            const short8v B1 = *(const short8v*)(smem + base + 3072 + rA + kbr);
            acc[q][0][0] = __builtin_amdgcn_mfma_f32_16x16x32_bf16(A0, B0, acc[q][0][0], 0, 0, 0);
            acc[q][0][1] = __builtin_amdgcn_mfma_f32_16x16x32_bf16(A0, B1, acc[q][0][1], 0, 0, 0);
            acc[q][1][0] = __builtin_amdgcn_mfma_f32_16x16x32_bf16(A1, B0, acc[q][1][0], 0, 0, 0);
            acc[q][1][1] = __builtin_amdgcn_mfma_f32_16x16x32_bf16(A1, B1, acc[q][1][1], 0, 0, 0);
        }
    };
    auto dump = [&](int dh) {                            // olds transpose + stores
#pragma unroll
        for (int q = 0; q < 2; ++q)
#pragma unroll
            for (int s = 0; s < 2; ++s)
#pragma unroll
                for (int dt = 0; dt < 2; ++dt)
#pragma unroll
                    for (int ri = 0; ri < 4; ++ri) {
                        const int ii = s * 16 + (l >> 4) * 4 + ri;
                        const int dl = dt * 16 + (l & 15);
                        LF[(ii * 32 + dl) * 33 + 2 * wv + q] = acc[q][s][dt][ri];
                    }
        SYNCX();
        float* ob = out + (size_t)b * 2048 * Tq + t0 + tl;
#pragma unroll 8
        for (int kk = 0; kk < 32; ++kk) {
            const int ch = kk * 64 + dh * 32 + slot;
            __builtin_nontemporal_store(LF[(kk * 32 + slot) * 33 + tl],
                                        &ob[(size_t)ch * Tq]);
        }
        SYNCX();                                         // region reused next
    };

    // ---- pipelined chunks: c = dh*2 + jh ----
    accClr();
    // c = 0 (dh0, jh0)
    stageP(0); stageC();
    SYNCX();
    issue(1);
    mfmaChunk();
    SYNCX();
    // c = 1 (dh0, jh1)
    stageP(1); stageC();
    SYNCX();
    issue(2);
    mfmaChunk();
    SYNCX();
    dump(0);
    accClr();
    // c = 2 (dh1, jh0)
    stageP(0); stageC();
    SYNCX();
    issue(3);
    mfmaChunk();
    SYNCX();
    // c = 3 (dh1, jh1)
    stageP(1); stageC();
    SYNCX();
    mfmaChunk();
    SYNCX();
    dump(1);
}

extern "C" void kernel_launch(void* const* d_in, const int* in_sizes, int n_in,
                              void* d_out, int out_size, void* d_ws, size_t ws_size,
                              hipStream_t stream) {
    const float* x  = (const float*)d_in[0];
    const float* xi = (const float*)d_in[1];
    float* out = (float*)d_out;
    attn_v14<<<dim3(NBLK), dim3(1024), 0, stream>>>(x, xi, out);
}